// Round 4
// baseline (2624.398 us; speedup 1.0000x reference)
//
#include <hip/hip_runtime.h>

// RecurrentSNN: B=256, T=1024, F=64, H=512, O=64
// out = concat(mem_rec [B,T,O], spk_rec [B,T,O]) f32.
//
// Round-4 = round-3 with the asm pinning fixed: "+v" tied constraints are
// only supported on SINGLE-register (scalar) operands on gfx950, so weights
// are pinned element-by-element (groups of 8) instead of as float4s.
//
// Design (unchanged):
//  1. Weights VGPR-resident, asm-pinned so the compiler cannot sink the
//     loads into the t-loop (round-1/2 pathology: VGPR_Count=80 proved the
//     128 "pinned" weight floats were re-fetched from L2 every step).
//  2. x per step: 16 wave-uniform global_load_dwordx4 (vmcnt domain),
//     issued one step ahead; the lgkm-only barrier does NOT drain them.
//  3. warm_x kernel pre-touches x into L3 (64 MB < 256 MB).
//  4. reduce/memo/stores wave-0 only; LDS only for the 8x64 partials,
//     double-buffered, ONE raw barrier per step.
// Arithmetic bit-identical to rounds 1/2 (same fma order/values).

namespace {
constexpr int kB = 256;
constexpr int kT = 1024;
constexpr int kF = 64;
constexpr int kH = 512;
constexpr int kO = 64;
constexpr float kBeta = 0.9f;
constexpr float kThresh = 1.0f;
constexpr int kThreads = 512;
}  // namespace

__global__ __launch_bounds__(256)
void warm_x_kernel(const float4* __restrict__ p, int n4) {
  float acc = 0.0f;
  for (int i = blockIdx.x * blockDim.x + threadIdx.x; i < n4;
       i += gridDim.x * blockDim.x) {
    const float4 v = p[i];
    acc += v.x + v.y + v.z + v.w;
  }
  asm volatile("" ::"v"(acc));  // keep loads live, no memory side effect
}

// spike float for in-slice index k (0..63) from this wave's ballot mask.
#define BITF(k) ((((k) < 32 ? (mlo >> (k)) : (mhi >> ((k)-32))) & 1u) \
                 ? 1.0f : 0.0f)

__global__ __launch_bounds__(kThreads, 2)
void snn_fused4(const float* __restrict__ x,
                const float* __restrict__ W_in,
                const float* __restrict__ b_in,
                const float* __restrict__ W_out,
                const float* __restrict__ b_out,
                float* __restrict__ out) {
  const int b = blockIdx.x;
  const int j = threadIdx.x;
  const int o = j & 63;
  const int s = j >> 6;

  __shared__ float red[2][8][64];  // [buf][slice][o]

  // ---- weights into scalar-SSA arrays (constant indices only) ----
  float win[kF];
  {
    const float4* wiv = reinterpret_cast<const float4*>(W_in) + j * 16;
#pragma unroll
    for (int q = 0; q < 16; ++q) {
      const float4 v = wiv[q];
      win[4 * q + 0] = v.x; win[4 * q + 1] = v.y;
      win[4 * q + 2] = v.z; win[4 * q + 3] = v.w;
    }
  }
  float wout[64];
  {
    const float4* wov =
        reinterpret_cast<const float4*>(W_out) + o * 128 + s * 16;
#pragma unroll
    for (int q = 0; q < 16; ++q) {
      const float4 v = wov[q];
      wout[4 * q + 0] = v.x; wout[4 * q + 1] = v.y;
      wout[4 * q + 2] = v.z; wout[4 * q + 3] = v.w;
    }
  }
  float bin_j = b_in[j];
  float bout_o = b_out[o];

  // ---- pin every weight scalar: asm is now the def point, loads cannot
  //      be rematerialized inside the t-loop. Scalar "+v" is supported. ----
#define PIN8(p)                                                            \
  asm volatile("" : "+v"((p)[0]), "+v"((p)[1]), "+v"((p)[2]),              \
                    "+v"((p)[3]), "+v"((p)[4]), "+v"((p)[5]),              \
                    "+v"((p)[6]), "+v"((p)[7]))
  PIN8(win + 0);  PIN8(win + 8);  PIN8(win + 16); PIN8(win + 24);
  PIN8(win + 32); PIN8(win + 40); PIN8(win + 48); PIN8(win + 56);
  PIN8(wout + 0);  PIN8(wout + 8);  PIN8(wout + 16); PIN8(wout + 24);
  PIN8(wout + 32); PIN8(wout + 40); PIN8(wout + 48); PIN8(wout + 56);
#undef PIN8
  asm volatile("" : "+v"(bin_j), "+v"(bout_o));

  // ---- carried state ----
  float mem1 = 0.0f, rst1 = 0.0f;
  float memo = 0.0f, rsto = 0.0f;
  unsigned long long mask = 0ull;

  const float4* xv = reinterpret_cast<const float4*>(x + (size_t)b * kT * kF);
  float* out_mem = out + (size_t)b * kT * kO + o;
  float* out_spk = out_mem + (size_t)kB * kT * kO;

  // wave-uniform x row in VGPRs (vmcnt-domain prefetch, one step ahead)
  float4 x0, x1, x2, x3, x4, x5, x6, x7, x8, x9, x10, x11, x12, x13, x14, x15;

#define LOADX(tt)                                                          \
  do {                                                                     \
    const float4* xp = xv + (size_t)(tt) * 16;                             \
    x0 = xp[0]; x1 = xp[1]; x2 = xp[2]; x3 = xp[3];                        \
    x4 = xp[4]; x5 = xp[5]; x6 = xp[6]; x7 = xp[7];                        \
    x8 = xp[8]; x9 = xp[9]; x10 = xp[10]; x11 = xp[11];                    \
    x12 = xp[12]; x13 = xp[13]; x14 = xp[14]; x15 = xp[15];                \
  } while (0)

  // raw barrier draining lgkm only (ds_write); vmcnt loads stay in flight.
#define BARRIER() asm volatile("s_waitcnt lgkmcnt(0)\n\ts_barrier" ::: "memory")

#define L1Q(q)                                                             \
  c0 = fmaf(x##q.x, win[4 * q + 0], c0);                                   \
  c1 = fmaf(x##q.y, win[4 * q + 1], c1);                                   \
  c2 = fmaf(x##q.z, win[4 * q + 2], c2);                                   \
  c3 = fmaf(x##q.w, win[4 * q + 3], c3);

#define LAYER1()                                                           \
  do {                                                                     \
    float c0 = bin_j, c1 = 0.0f, c2 = 0.0f, c3 = 0.0f;                     \
    L1Q(0) L1Q(1) L1Q(2) L1Q(3) L1Q(4) L1Q(5) L1Q(6) L1Q(7)                \
    L1Q(8) L1Q(9) L1Q(10) L1Q(11) L1Q(12) L1Q(13) L1Q(14) L1Q(15)          \
    const float cur1 = (c0 + c1) + (c2 + c3);                              \
    mem1 = kBeta * mem1 + cur1 - rst1;                                     \
    const bool p = mem1 > kThresh;                                         \
    mask = __ballot(p);                                                    \
    rst1 = p ? 1.0f : 0.0f;                                                \
  } while (0)

#define L2Q(q)                                                             \
  a0 = fmaf(BITF(4 * q + 0), wout[4 * q + 0], a0);                         \
  a1 = fmaf(BITF(4 * q + 1), wout[4 * q + 1], a1);                         \
  a2 = fmaf(BITF(4 * q + 2), wout[4 * q + 2], a2);                         \
  a3 = fmaf(BITF(4 * q + 3), wout[4 * q + 3], a3);

#define LAYER2(buf)                                                        \
  do {                                                                     \
    const unsigned mlo = (unsigned)mask;                                   \
    const unsigned mhi = (unsigned)(mask >> 32);                           \
    float a0 = 0.0f, a1 = 0.0f, a2 = 0.0f, a3 = 0.0f;                      \
    L2Q(0) L2Q(1) L2Q(2) L2Q(3) L2Q(4) L2Q(5) L2Q(6) L2Q(7)                \
    L2Q(8) L2Q(9) L2Q(10) L2Q(11) L2Q(12) L2Q(13) L2Q(14) L2Q(15)         \
    red[(buf)][s][o] = (a0 + a1) + (a2 + a3);                              \
  } while (0)

#define REDUCE_STORE(tt)                                                   \
  do {                                                                     \
    if (s == 0) {                                                          \
      const int buf = (tt) & 1;                                            \
      float co = bout_o;                                                   \
      co += red[buf][0][o]; co += red[buf][1][o];                          \
      co += red[buf][2][o]; co += red[buf][3][o];                          \
      co += red[buf][4][o]; co += red[buf][5][o];                          \
      co += red[buf][6][o]; co += red[buf][7][o];                          \
      memo = kBeta * memo + co - rsto;                                     \
      const float so = (memo > kThresh) ? 1.0f : 0.0f;                     \
      rsto = so;                                                           \
      out_mem[(tt) * kO] = memo;                                           \
      out_spk[(tt) * kO] = so;                                             \
    }                                                                      \
  } while (0)

  // ---- prologue ----
  LOADX(0);
  LAYER1();   // mask(0); compiler inserts the vmcnt wait for x(0)
  LOADX(1);   // in flight across the next barrier (vmcnt not drained)

  // ---- main loop ----
  for (int t = 1; t < kT; ++t) {
    LAYER2((t - 1) & 1);      // uses mask(t-1); ds_write red
    BARRIER();                // drains lgkm only; red visible
    REDUCE_STORE(t - 1);      // wave 0
    LAYER1();                 // consumes x(t) -> mask(t)
    const int tn = (t + 1 < kT) ? (t + 1) : (kT - 1);
    LOADX(tn);                // issue x(t+1); lands during next L2+barrier
  }

  // ---- epilogue: step T-1 layer2 + reduce ----
  LAYER2((kT - 1) & 1);
  BARRIER();
  REDUCE_STORE(kT - 1);

#undef LOADX
#undef BARRIER
#undef L1Q
#undef LAYER1
#undef L2Q
#undef LAYER2
#undef REDUCE_STORE
}

extern "C" void kernel_launch(void* const* d_in, const int* in_sizes, int n_in,
                              void* d_out, int out_size, void* d_ws,
                              size_t ws_size, hipStream_t stream) {
  const float* x = (const float*)d_in[0];
  const float* W_in = (const float*)d_in[1];
  const float* b_in = (const float*)d_in[2];
  const float* W_out = (const float*)d_in[3];
  const float* b_out = (const float*)d_in[4];
  float* out = (float*)d_out;

  const int n4 = kB * kT * kF / 4;
  hipLaunchKernelGGL(warm_x_kernel, dim3(1024), dim3(256), 0, stream,
                     (const float4*)x, n4);
  hipLaunchKernelGGL(snn_fused4, dim3(kB), dim3(kThreads), 0, stream,
                     x, W_in, b_in, W_out, b_out, out);
}

// Round 5
// 1101.470 us; speedup vs baseline: 2.3826x; 2.3826x over previous
//
#include <hip/hip_runtime.h>

// RecurrentSNN: B=256, T=1024, F=64, H=512, O=64
// out = concat(mem_rec [B,T,O], spk_rec [B,T,O]) f32.
//
// Round-5: force TRUE weight residency.
//  - amdgpu_waves_per_eu(2,2): exactly 2 waves/EU -> 256 VGPR budget/wave.
//    (Round 4: launch_bounds min=2 let the allocator target 4 waves/EU,
//    VGPR=108 < 128 pinned floats -> scratch spill -> 2.6 ms.)
//  - Scalar asm pins kept: the asm is the def point, weight loads cannot be
//    sunk/rematerialized into the t-loop (rounds 1/2 pathology: per-step
//    64-line gathers of W_in/W_out, ~2000 cy/CU/step).
//  - x(t+1) prefetch: 16 wave-uniform global_load_dwordx4 (vmcnt domain),
//    NOT drained by the lgkm-only barrier.
//  - ONE raw barrier/step; LDS only for the 8x64 partial reduce (dbuf).
//  - Reduce split: wave0 issues the 8 ds_reads BEFORE layer1, sums after
//    (hides ~120cy LDS latency under 64 fma).
//  - Layer-2 bit->float split across pipes, bit-identical arithmetic:
//      k in 0..31:  uniform SGPR select + v_fma   (2 SALU + 1 VALU)
//      k in 32..63: v_bfe_i32 + v_and + v_add_f32 (3 VALU, 0 SALU)
//    fma(0/1,w,a) == a + (w & bitmask) exactly (incl. signed-zero cases).

namespace {
constexpr int kB = 256;
constexpr int kT = 1024;
constexpr int kF = 64;
constexpr int kH = 512;
constexpr int kO = 64;
constexpr float kBeta = 0.9f;
constexpr float kThresh = 1.0f;
constexpr int kThreads = 512;
}  // namespace

__global__ __launch_bounds__(256)
void warm_x_kernel(const float4* __restrict__ p, int n4) {
  float acc = 0.0f;
  for (int i = blockIdx.x * blockDim.x + threadIdx.x; i < n4;
       i += gridDim.x * blockDim.x) {
    const float4 v = p[i];
    acc += v.x + v.y + v.z + v.w;
  }
  asm volatile("" ::"v"(acc));  // keep loads live, no memory side effect
}

__global__ __launch_bounds__(kThreads)
__attribute__((amdgpu_waves_per_eu(2, 2)))
void snn_fused5(const float* __restrict__ x,
                const float* __restrict__ W_in,
                const float* __restrict__ b_in,
                const float* __restrict__ W_out,
                const float* __restrict__ b_out,
                float* __restrict__ out) {
  const int b = blockIdx.x;
  const int j = threadIdx.x;
  const int o = j & 63;
  const int s = j >> 6;

  __shared__ float red[2][8][64];  // [buf][slice][o]

  // ---- weights into scalar-SSA arrays (constant indices only) ----
  float win[kF];
  {
    const float4* wiv = reinterpret_cast<const float4*>(W_in) + j * 16;
#pragma unroll
    for (int q = 0; q < 16; ++q) {
      const float4 v = wiv[q];
      win[4 * q + 0] = v.x; win[4 * q + 1] = v.y;
      win[4 * q + 2] = v.z; win[4 * q + 3] = v.w;
    }
  }
  float wout[64];
  {
    const float4* wov =
        reinterpret_cast<const float4*>(W_out) + o * 128 + s * 16;
#pragma unroll
    for (int q = 0; q < 16; ++q) {
      const float4 v = wov[q];
      wout[4 * q + 0] = v.x; wout[4 * q + 1] = v.y;
      wout[4 * q + 2] = v.z; wout[4 * q + 3] = v.w;
    }
  }
  float bin_j = b_in[j];
  float bout_o = b_out[o];

  // ---- pin every weight scalar (single-register "+v" is supported) ----
#define PIN8(p)                                                            \
  asm volatile("" : "+v"((p)[0]), "+v"((p)[1]), "+v"((p)[2]),              \
                    "+v"((p)[3]), "+v"((p)[4]), "+v"((p)[5]),              \
                    "+v"((p)[6]), "+v"((p)[7]))
  PIN8(win + 0);  PIN8(win + 8);  PIN8(win + 16); PIN8(win + 24);
  PIN8(win + 32); PIN8(win + 40); PIN8(win + 48); PIN8(win + 56);
  PIN8(wout + 0);  PIN8(wout + 8);  PIN8(wout + 16); PIN8(wout + 24);
  PIN8(wout + 32); PIN8(wout + 40); PIN8(wout + 48); PIN8(wout + 56);
#undef PIN8
  asm volatile("" : "+v"(bin_j), "+v"(bout_o));

  // ---- carried state ----
  float mem1 = 0.0f, rst1 = 0.0f;
  float memo = 0.0f, rsto = 0.0f;
  unsigned long long mask = 0ull;

  const float4* xv = reinterpret_cast<const float4*>(x + (size_t)b * kT * kF);
  float* out_mem = out + (size_t)b * kT * kO + o;
  float* out_spk = out_mem + (size_t)kB * kT * kO;

  // wave-uniform x row in VGPRs (vmcnt-domain prefetch, one step ahead)
  float4 x0, x1, x2, x3, x4, x5, x6, x7, x8, x9, x10, x11, x12, x13, x14, x15;

#define LOADX(tt)                                                          \
  do {                                                                     \
    const float4* xp = xv + (size_t)(tt) * 16;                             \
    x0 = xp[0]; x1 = xp[1]; x2 = xp[2]; x3 = xp[3];                        \
    x4 = xp[4]; x5 = xp[5]; x6 = xp[6]; x7 = xp[7];                        \
    x8 = xp[8]; x9 = xp[9]; x10 = xp[10]; x11 = xp[11];                    \
    x12 = xp[12]; x13 = xp[13]; x14 = xp[14]; x15 = xp[15];                \
  } while (0)

  // raw barrier draining lgkm only (ds ops); vmcnt loads stay in flight.
#define BARRIER() asm volatile("s_waitcnt lgkmcnt(0)\n\ts_barrier" ::: "memory")

#define L1Q(q)                                                             \
  c0 = fmaf(x##q.x, win[4 * q + 0], c0);                                   \
  c1 = fmaf(x##q.y, win[4 * q + 1], c1);                                   \
  c2 = fmaf(x##q.z, win[4 * q + 2], c2);                                   \
  c3 = fmaf(x##q.w, win[4 * q + 3], c3);

#define LAYER1()                                                           \
  do {                                                                     \
    float c0 = bin_j, c1 = 0.0f, c2 = 0.0f, c3 = 0.0f;                     \
    L1Q(0) L1Q(1) L1Q(2) L1Q(3) L1Q(4) L1Q(5) L1Q(6) L1Q(7)                \
    L1Q(8) L1Q(9) L1Q(10) L1Q(11) L1Q(12) L1Q(13) L1Q(14) L1Q(15)          \
    const float cur1 = (c0 + c1) + (c2 + c3);                              \
    mem1 = kBeta * mem1 + cur1 - rst1;                                     \
    const bool p = mem1 > kThresh;                                         \
    mask = __ballot(p);                                                    \
    rst1 = p ? 1.0f : 0.0f;                                                \
  } while (0)

  // layer-2, low half: uniform-SGPR select + fma (SALU path)
#define L2QS(q)                                                            \
  {                                                                        \
    const float f0 = ((mlo >> (4 * (q) + 0)) & 1u) ? 1.0f : 0.0f;          \
    const float f1 = ((mlo >> (4 * (q) + 1)) & 1u) ? 1.0f : 0.0f;          \
    const float f2 = ((mlo >> (4 * (q) + 2)) & 1u) ? 1.0f : 0.0f;          \
    const float f3 = ((mlo >> (4 * (q) + 3)) & 1u) ? 1.0f : 0.0f;          \
    a0 = fmaf(f0, wout[4 * (q) + 0], a0);                                  \
    a1 = fmaf(f1, wout[4 * (q) + 1], a1);                                  \
    a2 = fmaf(f2, wout[4 * (q) + 2], a2);                                  \
    a3 = fmaf(f3, wout[4 * (q) + 3], a3);                                  \
  }

  // layer-2, high half: bfe_i32 (0/-1) & weight-bits, float add (VALU path)
#define L2E(acc, q, i)                                                     \
  acc = acc + __uint_as_float(                                             \
      (unsigned)__builtin_amdgcn_sbfe((int)vmhi, 4 * (q) + (i)-32, 1) &    \
      __float_as_uint(wout[4 * (q) + (i)]));
#define L2QV(q)                                                            \
  { L2E(a0, q, 0) L2E(a1, q, 1) L2E(a2, q, 2) L2E(a3, q, 3) }

#define LAYER2(buf)                                                        \
  do {                                                                     \
    const unsigned mlo = (unsigned)mask;                                   \
    unsigned vmhi = (unsigned)(mask >> 32);                                \
    asm volatile("" : "+v"(vmhi)); /* force VALU path for high half */     \
    float a0 = 0.0f, a1 = 0.0f, a2 = 0.0f, a3 = 0.0f;                      \
    L2QS(0) L2QS(1) L2QS(2) L2QS(3) L2QS(4) L2QS(5) L2QS(6) L2QS(7)        \
    L2QV(8) L2QV(9) L2QV(10) L2QV(11) L2QV(12) L2QV(13) L2QV(14) L2QV(15)  \
    red[(buf)][s][o] = (a0 + a1) + (a2 + a3);                              \
  } while (0)

  // ---- prologue ----
  LOADX(0);
  LAYER1();   // mask(0); compiler inserts the vmcnt wait for x(0)
  LOADX(1);   // in flight across the next barrier (vmcnt not drained)

  // ---- main loop ----
  for (int t = 1; t < kT; ++t) {
    LAYER2((t - 1) & 1);      // uses mask(t-1); ds_write red
    BARRIER();                // drains lgkm only; red visible

    // wave0: ISSUE reduce loads now, consume after LAYER1 (hide LDS latency)
    float r0, r1, r2, r3, r4, r5, r6, r7;
    const int buf = (t - 1) & 1;
    if (s == 0) {
      r0 = red[buf][0][o]; r1 = red[buf][1][o];
      r2 = red[buf][2][o]; r3 = red[buf][3][o];
      r4 = red[buf][4][o]; r5 = red[buf][5][o];
      r6 = red[buf][6][o]; r7 = red[buf][7][o];
    }

    LAYER1();                 // consumes x(t) -> mask(t)
    const int tn = (t + 1 < kT) ? (t + 1) : (kT - 1);
    LOADX(tn);                // issue x(t+1); lands during next L2+barrier

    if (s == 0) {
      float co = bout_o;
      co += r0; co += r1; co += r2; co += r3;
      co += r4; co += r5; co += r6; co += r7;
      memo = kBeta * memo + co - rsto;
      const float so = (memo > kThresh) ? 1.0f : 0.0f;
      rsto = so;
      out_mem[(t - 1) * kO] = memo;
      out_spk[(t - 1) * kO] = so;
    }
  }

  // ---- epilogue: step T-1 layer2 + reduce ----
  LAYER2((kT - 1) & 1);
  BARRIER();
  if (s == 0) {
    const int buf = (kT - 1) & 1;
    float co = bout_o;
    co += red[buf][0][o]; co += red[buf][1][o];
    co += red[buf][2][o]; co += red[buf][3][o];
    co += red[buf][4][o]; co += red[buf][5][o];
    co += red[buf][6][o]; co += red[buf][7][o];
    memo = kBeta * memo + co - rsto;
    const float so = (memo > kThresh) ? 1.0f : 0.0f;
    out_mem[(kT - 1) * kO] = memo;
    out_spk[(kT - 1) * kO] = so;
  }

#undef LOADX
#undef BARRIER
#undef L1Q
#undef LAYER1
#undef L2QS
#undef L2E
#undef L2QV
#undef LAYER2
}

extern "C" void kernel_launch(void* const* d_in, const int* in_sizes, int n_in,
                              void* d_out, int out_size, void* d_ws,
                              size_t ws_size, hipStream_t stream) {
  const float* x = (const float*)d_in[0];
  const float* W_in = (const float*)d_in[1];
  const float* b_in = (const float*)d_in[2];
  const float* W_out = (const float*)d_in[3];
  const float* b_out = (const float*)d_in[4];
  float* out = (float*)d_out;

  const int n4 = kB * kT * kF / 4;
  hipLaunchKernelGGL(warm_x_kernel, dim3(1024), dim3(256), 0, stream,
                     (const float4*)x, n4);
  hipLaunchKernelGGL(snn_fused5, dim3(kB), dim3(kThreads), 0, stream,
                     x, W_in, b_in, W_out, b_out, out);
}